// Round 12
// baseline (106.527 us; speedup 1.0000x reference)
//
#include <hip/hip_runtime.h>

#define B_    16
#define N_    4096
#define S_    1024
#define K_    32
#define DIN_  64
#define DINC_ 67
#define DOUT_ 64
#define ROWS_ (B_ * N_)
#define NCH   128            // 64 proj + 64 xp output columns
#define NTILE 28             // nonzero weight tiles (s0:8, s1:8, s2:4, s3:4, s4:4)
#define NFRAG (NTILE * 64)   // 1792 16B-chunks = 28 KB
#define ASTR  168            // LDS act row stride in ushorts (336 B = 21*16)
#define ALDSB (64 * ASTR * 2)          // 21504 B activations (ONLY LDS now)
// K-REORDER: k' = 0..63 -> x (w2), k' = 64..130 -> xc (w1), 131..159 zero.
// cmb row: 128 bf16 = [proj x64 | xp x64] = 256 B

typedef float f32x4 __attribute__((ext_vector_type(4)));
typedef short s16x8 __attribute__((ext_vector_type(8)));

static __device__ __forceinline__ unsigned short f2bf(float f) {
    unsigned int u = __float_as_uint(f);
    u = (u + 0x7fffu + ((u >> 16) & 1u)) >> 16;   // RNE
    return (unsigned short)u;
}
static __device__ __forceinline__ float bf2f(unsigned short h) {
    return __uint_as_float((unsigned int)h << 16);
}
static __device__ __forceinline__ unsigned int pack2(float a, float b) {
    return (unsigned int)f2bf(a) | ((unsigned int)f2bf(b) << 16);
}

// ---------------------------------------------------------------------------
// Prep: build the 28 nonzero MFMA weight-fragment tiles (identical to r9).
// ---------------------------------------------------------------------------
__global__ __launch_bounds__(256) void prep_kernel(
    const float* __restrict__ w1, const float* __restrict__ w2,
    const int* __restrict__ use_x_p, uint4* __restrict__ wf)
{
    const int id = blockIdx.x * 256 + threadIdx.x;
    if (id >= NFRAG) return;
    const int tile = id >> 6;
    const int l    = id & 63;
    const int s    = (tile < 16) ? (tile >> 3) : (2 + ((tile - 16) >> 2));
    const int nt   = (tile < 16) ? (tile & 7)  : ((tile - 16) & 3);
    const int q    = l >> 4, m = l & 15;
    const int c    = nt * 16 + m;
    const int ux   = use_x_p[0];

    unsigned int w[4];
#pragma unroll
    for (int p = 0; p < 4; ++p) {
        unsigned short h[2];
#pragma unroll
        for (int e = 0; e < 2; ++e) {
            const int k = s * 32 + q * 8 + p * 2 + e;   // k'
            float v = 0.f;
            if (c < 64) {
                if (k < 64)         v = ux ? w2[c * DIN_ + k] : 0.f;
                else if (k < 131)   v = w1[c * DINC_ + (k - 64)];
            } else {
                if (k < 64)         v = w2[(c - 64) * DIN_ + k];
            }
            h[e] = f2bf(v);
        }
        w[p] = (unsigned int)h[0] | ((unsigned int)h[1] << 16);
    }
    wf[id] = make_uint4(w[0], w[1], w[2], w[3]);
}

// ---------------------------------------------------------------------------
// Kernel 1: projection via MFMA 16x16x32 bf16.
// Round-12 change (single variable vs r9): wf is NOT staged to LDS. The
// B-operand fragment read bfr[(s*8+nt)*64 + l] is 16 B/lane perfectly
// coalesced from GLOBAL — wf is 28 KB and L2-resident on every XCD after the
// first touch, so these are ~L2-hit loads that the 16 waves/CU easily hide.
// Effect: LDS 50176 -> 21504 B (activations only), block residency 3 -> 4+
// (__launch_bounds__(256,4) caps VGPR at 128). Everything else identical to
// the best-measured r9 kernel.
// ---------------------------------------------------------------------------
__global__ __launch_bounds__(256, 4) void proj_kernel(
    const float* __restrict__ x, const float* __restrict__ xcm,
    const uint4* __restrict__ wf, const float* __restrict__ bias,
    unsigned short* __restrict__ cmb)
{
    __shared__ char smem[ALDSB];              // 21504 B -> LDS allows 7 blocks/CU
    unsigned short* lact = (unsigned short*)smem;
    unsigned int*  ldsd  = (unsigned int*)smem;

    const int t    = threadIdx.x;
    // XCD swizzle: xcd g computes batches 2g,2g+1 (matches gather's reader slab)
    const int row0 = (blockIdx.x & 7) * (ROWS_ / 8) + (blockIdx.x >> 3) * 64;

    {
        const float4* sx4 = (const float4*)(x + (size_t)row0 * DIN_);
#pragma unroll
        for (int j = 0; j < 4; ++j) {
            const int idx = j * 256 + t;           // 0..1023
            const float4 v = sx4[idx];
            const int row = idx >> 4, f4 = idx & 15;
            *(uint2*)(ldsd + row * 84 + f4 * 2) =
                make_uint2(pack2(v.x, v.y), pack2(v.z, v.w));
        }
    }
    {
        const float4* sc4 = (const float4*)(xcm + (size_t)row0 * DINC_);
#pragma unroll
        for (int j = 0; j < 5; ++j) {
            const int idx = j * 256 + t;
            if (j < 4 || idx < 1072) {
                const float4 v = sc4[idx];
                const float e4[4] = {v.x, v.y, v.z, v.w};
#pragma unroll
                for (int e = 0; e < 4; ++e) {
                    const int ee  = 4 * idx + e;
                    const int row = ee / 67;        // compiler magic-div
                    const int d   = ee - row * 67;
                    lact[row * ASTR + 64 + d] = f2bf(e4[e]);
                }
            }
        }
    }
    if (t < 64) lact[t * ASTR + 131] = 0;
    for (int i = t; i < 64 * 14; i += 256) {
        const int row = i / 14, j2 = i - row * 14;
        ldsd[row * 84 + 66 + j2] = 0;
    }
    __syncthreads();

    const int l = t & 63;
    const int w = __builtin_amdgcn_readfirstlane(t >> 6);
    const int q = l >> 4, m = l & 15;

    const unsigned short* arow = lact + (w * 16 + m) * ASTR;
    s16x8 af[5];
#pragma unroll
    for (int s = 0; s < 5; ++s)
        af[s] = *(const s16x8*)(arow + s * 32 + q * 8);

    const s16x8* bfr = (const s16x8*)wf;       // GLOBAL, L2-resident

    f32x4 acc[8];
#pragma unroll
    for (int nt = 0; nt < 8; ++nt) acc[nt] = (f32x4){0.f, 0.f, 0.f, 0.f};

#pragma unroll
    for (int s = 0; s < 2; ++s)                  // full tiles: all 8 ntiles
#pragma unroll
        for (int nt = 0; nt < 8; ++nt)
            acc[nt] = __builtin_amdgcn_mfma_f32_16x16x32_bf16(
                bfr[(s * 8 + nt) * 64 + l], af[s], acc[nt], 0, 0, 0);
#pragma unroll
    for (int s = 2; s < 5; ++s)                  // proj-only tiles: ntiles 0..3
#pragma unroll
        for (int nt = 0; nt < 4; ++nt)
            acc[nt] = __builtin_amdgcn_mfma_f32_16x16x32_bf16(
                bfr[(16 + (s - 2) * 4 + nt) * 64 + l], af[s], acc[nt], 0, 0, 0);

    const int row_g = row0 + w * 16 + m;
    unsigned short* rowp = cmb + (size_t)row_g * NCH;
    const int chq = q * 4;
#pragma unroll
    for (int nt = 0; nt < 8; ++nt) {
        f32x4 a = acc[nt];
        if (nt < 4) {
            const float4 bv = *(const float4*)(bias + nt * 16 + chq);
            a[0] += bv.x; a[1] += bv.y; a[2] += bv.z; a[3] += bv.w;
        }
        *(uint2*)(rowp + nt * 16 + chq) =
            make_uint2(pack2(a[0], a[1]), pack2(a[2], a[3]));
    }
}

// ---------------------------------------------------------------------------
// Kernel 2: gather + masked max + center subtraction, 2 pairs per wave —
// exact r9 version (best measured config).
// ---------------------------------------------------------------------------
__global__ __launch_bounds__(256) void gather_max_kernel(
    const int* __restrict__ indexes, const unsigned short* __restrict__ cmb,
    const int* __restrict__ use_x_p, float* __restrict__ out)
{
    const int lane = threadIdx.x & 63;
    const int h    = lane >> 5;
    const int ln   = lane & 31;
    const int wv   = __builtin_amdgcn_readfirstlane(threadIdx.x >> 6);
    const int grp  = (blockIdx.x & 7) * 1024 + (blockIdx.x >> 3) * 4 + wv; // 8192 groups
    const int pairA = grp * 2;
    const int b     = grp >> 9;          // 512 groups per batch
    const int ux    = use_x_p[0];

    const int* iA = indexes + (size_t)pairA * K_;       // uniform -> s_load
    const int* iB = iA + K_;
    const char* cb = (const char*)cmb + (size_t)b * N_ * 256;

    const float NEG = -__builtin_inff();
    float m0 = NEG, m1 = NEG;
#pragma unroll
    for (int k = 0; k < K_; ++k) {
        const int ia = iA[k], ib = iB[k];
        const int ik = h ? ib : ia;
        const int iku = ik < 0 ? 0 : ik;
        const unsigned int v = *(const unsigned int*)(cb + ((size_t)iku << 8) + ln * 4);
        const bool inv = ik < 0;
        m0 = fmaxf(m0, inv ? NEG : bf2f((unsigned short)(v & 0xffff)));
        m1 = fmaxf(m1, inv ? NEG : bf2f((unsigned short)(v >> 16)));
    }
    if (ux) {
        const int i0 = h ? iB[0] : iA[0];               // center, always valid
        const unsigned int c = *(const unsigned int*)(cb + ((size_t)i0 << 8) + 128 + ln * 4);
        m0 -= bf2f((unsigned short)(c & 0xffff));
        m1 -= bf2f((unsigned short)(c >> 16));
    }
    const int pair = pairA + h;
    *(float2*)(out + (size_t)pair * 64 + ln * 2) = make_float2(m0, m1);
}

// ---------------------------------------------------------------------------
// Fallback (ws too small): fully fused, recomputes projections per gather.
// ---------------------------------------------------------------------------
__global__ __launch_bounds__(256, 1) void fused_fallback_kernel(
    const float* __restrict__ x, const float* __restrict__ xcm,
    const int* __restrict__ indexes,
    const float* __restrict__ w1, const float* __restrict__ w2,
    const float* __restrict__ bias, const int* __restrict__ use_x_p,
    float* __restrict__ out)
{
    const int lane = threadIdx.x & 63;
    const int pair = (blockIdx.x * blockDim.x + threadIdx.x) >> 6;
    const int b    = pair >> 10;
    const int ux   = use_x_p[0];

    float W1[DINC_];
#pragma unroll
    for (int j = 0; j < DINC_; ++j) W1[j] = w1[lane * DINC_ + j];
    float W2[DIN_];
#pragma unroll
    for (int j = 0; j < DIN_; ++j) W2[j] = w2[lane * DIN_ + j];
    const float bv = bias[lane];

    const int* idxp  = indexes + (size_t)pair * K_;
    const int  myidx = idxp[lane & 31];

    const float NEG = -__builtin_inff();
    float m = NEG;
    for (int k = 0; k < K_; ++k) {
        const int ik = __shfl(myidx, k, 64);
        if (ik < 0) continue;
        const float* xc_row = xcm + ((size_t)b * N_ + ik) * DINC_;
        float a1 = bv;
#pragma unroll
        for (int j = 0; j < DINC_; ++j) a1 += xc_row[j] * W1[j];
        if (ux) {
            const float* x_row = x + ((size_t)b * N_ + ik) * DIN_;
            float a2 = 0.f;
#pragma unroll
            for (int j = 0; j < DIN_; ++j) a2 += x_row[j] * W2[j];
            a1 += a2;
        }
        m = fmaxf(m, a1);
    }
    if (ux) {
        const int i0 = __shfl(myidx, 0, 64);
        const float* x_row = x + ((size_t)b * N_ + i0) * DIN_;
        float a2 = 0.f;
#pragma unroll
        for (int j = 0; j < DIN_; ++j) a2 += x_row[j] * W2[j];
        m -= a2;
    }
    out[(size_t)pair * DOUT_ + lane] = m;
}

extern "C" void kernel_launch(void* const* d_in, const int* in_sizes, int n_in,
                              void* d_out, int out_size, void* d_ws, size_t ws_size,
                              hipStream_t stream)
{
    const float* x    = (const float*)d_in[0];
    const float* xcm  = (const float*)d_in[1];
    const int*   idx  = (const int*)d_in[2];
    const float* w1   = (const float*)d_in[3];
    const float* w2   = (const float*)d_in[4];
    const float* bias = (const float*)d_in[5];
    const int*   ux   = (const int*)d_in[6];
    float* out = (float*)d_out;

    const size_t cmb_bytes = (size_t)ROWS_ * NCH * sizeof(unsigned short); // 16 MiB
    const size_t wf_bytes  = (size_t)NFRAG * 16;                           // 28 KB
    const int npairs = B_ * S_;   // 16384

    if (ws_size >= cmb_bytes + wf_bytes) {
        unsigned short* cmb = (unsigned short*)d_ws;
        uint4* wf = (uint4*)((char*)d_ws + cmb_bytes);

        prep_kernel<<<(NFRAG + 255) / 256, 256, 0, stream>>>(w1, w2, ux, wf);
        proj_kernel<<<ROWS_ / 64, 256, 0, stream>>>(x, xcm, wf, bias, cmb);
        gather_max_kernel<<<(npairs / 2) / 4, 256, 0, stream>>>(idx, cmb, ux, out);
    } else {
        fused_fallback_kernel<<<npairs / 4, 256, 0, stream>>>(x, xcm, idx, w1, w2,
                                                              bias, ux, out);
    }
}

// Round 13
// 102.603 us; speedup vs baseline: 1.0382x; 1.0382x over previous
//
#include <hip/hip_runtime.h>

#define B_    16
#define N_    4096
#define S_    1024
#define K_    32
#define DIN_  64
#define DINC_ 67
#define DOUT_ 64
#define ROWS_ (B_ * N_)
#define NCH   128            // 64 proj + 64 xp output columns
#define NTILE 28             // nonzero weight tiles (s0:8, s1:8, s2:4, s3:4, s4:4)
#define ASTR  168            // LDS act row stride in ushorts (336 B = 21*16)
#define WLDSB (NTILE * 64 * 16)        // 28672 B weight frags
#define ALDSB (64 * ASTR * 2)          // 21504 B activations
// K-REORDER: k' = 0..63 -> x (w2), k' = 64..130 -> xc (w1), 131..159 zero.
// cmb row: 128 bf16 = [proj x64 | xp x64] = 256 B

typedef float f32x4 __attribute__((ext_vector_type(4)));
typedef short s16x8 __attribute__((ext_vector_type(8)));

static __device__ __forceinline__ unsigned short f2bf(float f) {
    unsigned int u = __float_as_uint(f);
    u = (u + 0x7fffu + ((u >> 16) & 1u)) >> 16;   // RNE
    return (unsigned short)u;
}
static __device__ __forceinline__ float bf2f(unsigned short h) {
    return __uint_as_float((unsigned int)h << 16);
}
static __device__ __forceinline__ unsigned int pack2(float a, float b) {
    return (unsigned int)f2bf(a) | ((unsigned int)f2bf(b) << 16);
}

// ---------------------------------------------------------------------------
// Kernel 1 (round-13): projection via MFMA 16x16x32 bf16 with INTEGRATED
// weight-fragment build (prep dispatch eliminated; 34 KB of raw weights are
// L2-resident for all but the first blocks).
// Frag layout identical to r9: chunk = tile*64 + (q*16+m); element j =
// W[k'=s*32+q*8+j][c=nt*16+m]; tiles 0..15: s=tile>>3,nt=tile&7 (x/w2 part,
// proj cols ux-scaled, xp cols raw); tiles 16..27: s=2+((tile-16)>>2),
// nt=(tile-16)&3 (xc/w1 part, proj cols only).
// Act staging / MFMA loop / epilogue byte-identical to the best-measured r9.
// ---------------------------------------------------------------------------
__global__ __launch_bounds__(256) void proj_kernel(
    const float* __restrict__ x, const float* __restrict__ xcm,
    const float* __restrict__ w1, const float* __restrict__ w2,
    const float* __restrict__ bias, const int* __restrict__ use_x_p,
    unsigned short* __restrict__ cmb)
{
    __shared__ char smem[WLDSB + ALDSB];      // 50176 B -> 3 blocks/CU
    uint4* ldsb          = (uint4*)smem;                    // frag chunks
    unsigned short* lwb  = (unsigned short*)smem;           // frag region, b16 view
    unsigned short* lact = (unsigned short*)(smem + WLDSB); // activations
    unsigned int*  ldsd  = (unsigned int*)lact;

    const int t    = threadIdx.x;
    // XCD swizzle: xcd g computes batches 2g,2g+1 (matches gather's reader slab)
    const int row0 = (blockIdx.x & 7) * (ROWS_ / 8) + (blockIdx.x >> 3) * 64;
    const int ux   = use_x_p[0];

    // ---- phase 0: pre-zero the s=4 tiles (chunks 1536..1791, 4 KB) so the
    // w1 scatter only needs to fill k'=128..130 ----
    ldsb[1536 + t] = make_uint4(0u, 0u, 0u, 0u);
    __syncthreads();

    // ---- w2 -> s{0,1} frag chunks: 512 chunks, 2 per thread. One aligned
    // 8-float row chunk == one frag chunk. ----
#pragma unroll
    for (int it = 0; it < 2; ++it) {
        const int wid = it * 256 + t;              // 0..511
        const int c   = wid >> 3, kc = wid & 7;    // kc -> (s,q)
        const int s   = kc >> 2,  q  = kc & 3;
        const float4 v0 = *(const float4*)(w2 + c * DIN_ + kc * 8);
        const float4 v1 = *(const float4*)(w2 + c * DIN_ + kc * 8 + 4);
        uint4 pk;
        pk.x = pack2(v0.x, v0.y); pk.y = pack2(v0.z, v0.w);
        pk.z = pack2(v1.x, v1.y); pk.w = pack2(v1.z, v1.w);
        const int lane = q * 16 + (c & 15);
        ldsb[(s * 8 + 4 + (c >> 4)) * 64 + lane] = pk;                   // xp col
        ldsb[(s * 8 + (c >> 4)) * 64 + lane] =
            ux ? pk : make_uint4(0u, 0u, 0u, 0u);                        // proj col
    }

    // ---- w1 -> s{2,3,4} frag chunks: flat stream of 4288 floats = 1072 f4,
    // per-element b16 scatter (same pattern as the xc staging) ----
    {
        const float4* w14 = (const float4*)w1;
#pragma unroll
        for (int jj = 0; jj < 5; ++jj) {
            const int idx = jj * 256 + t;
            if (jj < 4 || idx < 1072) {
                const float4 v = w14[idx];
                const float e4[4] = {v.x, v.y, v.z, v.w};
#pragma unroll
                for (int e = 0; e < 4; ++e) {
                    const int ee = 4 * idx + e;
                    const int c  = ee / 67;                 // compiler magic-div
                    const int kk = ee - c * 67 + 64;        // k' = 64..130
                    const int s  = kk >> 5;                 // 2..4
                    const int q  = (kk >> 3) & 3;
                    const int j  = kk & 7;
                    const int chunk = (16 + (s - 2) * 4 + (c >> 4)) * 64
                                      + q * 16 + (c & 15);
                    lwb[chunk * 8 + j] = f2bf(e4[e]);
                }
            }
        }
    }

    // ---- activations (identical to r9) ----
    {
        const float4* sx4 = (const float4*)(x + (size_t)row0 * DIN_);
#pragma unroll
        for (int j = 0; j < 4; ++j) {
            const int idx = j * 256 + t;           // 0..1023
            const float4 v = sx4[idx];
            const int row = idx >> 4, f4 = idx & 15;
            *(uint2*)(ldsd + row * 84 + f4 * 2) =
                make_uint2(pack2(v.x, v.y), pack2(v.z, v.w));
        }
    }
    {
        const float4* sc4 = (const float4*)(xcm + (size_t)row0 * DINC_);
#pragma unroll
        for (int j = 0; j < 5; ++j) {
            const int idx = j * 256 + t;
            if (j < 4 || idx < 1072) {
                const float4 v = sc4[idx];
                const float e4[4] = {v.x, v.y, v.z, v.w};
#pragma unroll
                for (int e = 0; e < 4; ++e) {
                    const int ee  = 4 * idx + e;
                    const int row = ee / 67;        // compiler magic-div
                    const int d   = ee - row * 67;
                    lact[row * ASTR + 64 + d] = f2bf(e4[e]);
                }
            }
        }
    }
    if (t < 64) lact[t * ASTR + 131] = 0;
    for (int i = t; i < 64 * 14; i += 256) {
        const int row = i / 14, j2 = i - row * 14;
        ldsd[row * 84 + 66 + j2] = 0;
    }
    __syncthreads();

    const int l = t & 63;
    const int w = __builtin_amdgcn_readfirstlane(t >> 6);
    const int q = l >> 4, m = l & 15;

    const unsigned short* arow = lact + (w * 16 + m) * ASTR;
    s16x8 af[5];
#pragma unroll
    for (int s = 0; s < 5; ++s)
        af[s] = *(const s16x8*)(arow + s * 32 + q * 8);

    const s16x8* bfr = (const s16x8*)ldsb;

    f32x4 acc[8];
#pragma unroll
    for (int nt = 0; nt < 8; ++nt) acc[nt] = (f32x4){0.f, 0.f, 0.f, 0.f};

#pragma unroll
    for (int s = 0; s < 2; ++s)                  // full tiles: all 8 ntiles
#pragma unroll
        for (int nt = 0; nt < 8; ++nt)
            acc[nt] = __builtin_amdgcn_mfma_f32_16x16x32_bf16(
                bfr[(s * 8 + nt) * 64 + l], af[s], acc[nt], 0, 0, 0);
#pragma unroll
    for (int s = 2; s < 5; ++s)                  // proj-only tiles: ntiles 0..3
#pragma unroll
        for (int nt = 0; nt < 4; ++nt)
            acc[nt] = __builtin_amdgcn_mfma_f32_16x16x32_bf16(
                bfr[(16 + (s - 2) * 4 + nt) * 64 + l], af[s], acc[nt], 0, 0, 0);

    const int row_g = row0 + w * 16 + m;
    unsigned short* rowp = cmb + (size_t)row_g * NCH;
    const int chq = q * 4;
#pragma unroll
    for (int nt = 0; nt < 8; ++nt) {
        f32x4 a = acc[nt];
        if (nt < 4) {
            const float4 bv = *(const float4*)(bias + nt * 16 + chq);
            a[0] += bv.x; a[1] += bv.y; a[2] += bv.z; a[3] += bv.w;
        }
        *(uint2*)(rowp + nt * 16 + chq) =
            make_uint2(pack2(a[0], a[1]), pack2(a[2], a[3]));
    }
}

// ---------------------------------------------------------------------------
// Kernel 2: gather + masked max + center subtraction, 2 pairs per wave —
// exact r9 version (best measured config).
// ---------------------------------------------------------------------------
__global__ __launch_bounds__(256) void gather_max_kernel(
    const int* __restrict__ indexes, const unsigned short* __restrict__ cmb,
    const int* __restrict__ use_x_p, float* __restrict__ out)
{
    const int lane = threadIdx.x & 63;
    const int h    = lane >> 5;
    const int ln   = lane & 31;
    const int wv   = __builtin_amdgcn_readfirstlane(threadIdx.x >> 6);
    const int grp  = (blockIdx.x & 7) * 1024 + (blockIdx.x >> 3) * 4 + wv; // 8192 groups
    const int pairA = grp * 2;
    const int b     = grp >> 9;          // 512 groups per batch
    const int ux    = use_x_p[0];

    const int* iA = indexes + (size_t)pairA * K_;       // uniform -> s_load
    const int* iB = iA + K_;
    const char* cb = (const char*)cmb + (size_t)b * N_ * 256;

    const float NEG = -__builtin_inff();
    float m0 = NEG, m1 = NEG;
#pragma unroll
    for (int k = 0; k < K_; ++k) {
        const int ia = iA[k], ib = iB[k];
        const int ik = h ? ib : ia;
        const int iku = ik < 0 ? 0 : ik;
        const unsigned int v = *(const unsigned int*)(cb + ((size_t)iku << 8) + ln * 4);
        const bool inv = ik < 0;
        m0 = fmaxf(m0, inv ? NEG : bf2f((unsigned short)(v & 0xffff)));
        m1 = fmaxf(m1, inv ? NEG : bf2f((unsigned short)(v >> 16)));
    }
    if (ux) {
        const int i0 = h ? iB[0] : iA[0];               // center, always valid
        const unsigned int c = *(const unsigned int*)(cb + ((size_t)i0 << 8) + 128 + ln * 4);
        m0 -= bf2f((unsigned short)(c & 0xffff));
        m1 -= bf2f((unsigned short)(c >> 16));
    }
    const int pair = pairA + h;
    *(float2*)(out + (size_t)pair * 64 + ln * 2) = make_float2(m0, m1);
}

// ---------------------------------------------------------------------------
// Fallback (ws too small): fully fused, recomputes projections per gather.
// ---------------------------------------------------------------------------
__global__ __launch_bounds__(256, 1) void fused_fallback_kernel(
    const float* __restrict__ x, const float* __restrict__ xcm,
    const int* __restrict__ indexes,
    const float* __restrict__ w1, const float* __restrict__ w2,
    const float* __restrict__ bias, const int* __restrict__ use_x_p,
    float* __restrict__ out)
{
    const int lane = threadIdx.x & 63;
    const int pair = (blockIdx.x * blockDim.x + threadIdx.x) >> 6;
    const int b    = pair >> 10;
    const int ux   = use_x_p[0];

    float W1[DINC_];
#pragma unroll
    for (int j = 0; j < DINC_; ++j) W1[j] = w1[lane * DINC_ + j];
    float W2[DIN_];
#pragma unroll
    for (int j = 0; j < DIN_; ++j) W2[j] = w2[lane * DIN_ + j];
    const float bv = bias[lane];

    const int* idxp  = indexes + (size_t)pair * K_;
    const int  myidx = idxp[lane & 31];

    const float NEG = -__builtin_inff();
    float m = NEG;
    for (int k = 0; k < K_; ++k) {
        const int ik = __shfl(myidx, k, 64);
        if (ik < 0) continue;
        const float* xc_row = xcm + ((size_t)b * N_ + ik) * DINC_;
        float a1 = bv;
#pragma unroll
        for (int j = 0; j < DINC_; ++j) a1 += xc_row[j] * W1[j];
        if (ux) {
            const float* x_row = x + ((size_t)b * N_ + ik) * DIN_;
            float a2 = 0.f;
#pragma unroll
            for (int j = 0; j < DIN_; ++j) a2 += x_row[j] * W2[j];
            a1 += a2;
        }
        m = fmaxf(m, a1);
    }
    if (ux) {
        const int i0 = __shfl(myidx, 0, 64);
        const float* x_row = x + ((size_t)b * N_ + i0) * DIN_;
        float a2 = 0.f;
#pragma unroll
        for (int j = 0; j < DIN_; ++j) a2 += x_row[j] * W2[j];
        m -= a2;
    }
    out[(size_t)pair * DOUT_ + lane] = m;
}

extern "C" void kernel_launch(void* const* d_in, const int* in_sizes, int n_in,
                              void* d_out, int out_size, void* d_ws, size_t ws_size,
                              hipStream_t stream)
{
    const float* x    = (const float*)d_in[0];
    const float* xcm  = (const float*)d_in[1];
    const int*   idx  = (const int*)d_in[2];
    const float* w1   = (const float*)d_in[3];
    const float* w2   = (const float*)d_in[4];
    const float* bias = (const float*)d_in[5];
    const int*   ux   = (const int*)d_in[6];
    float* out = (float*)d_out;

    const size_t cmb_bytes = (size_t)ROWS_ * NCH * sizeof(unsigned short); // 16 MiB
    const int npairs = B_ * S_;   // 16384

    if (ws_size >= cmb_bytes) {
        unsigned short* cmb = (unsigned short*)d_ws;
        proj_kernel<<<ROWS_ / 64, 256, 0, stream>>>(x, xcm, w1, w2, bias, ux, cmb);
        gather_max_kernel<<<(npairs / 2) / 4, 256, 0, stream>>>(idx, cmb, ux, out);
    } else {
        fused_fallback_kernel<<<npairs / 4, 256, 0, stream>>>(x, xcm, idx, w1, w2,
                                                              bias, ux, out);
    }
}